// Round 6
// baseline (9232.497 us; speedup 1.0000x reference)
//
#include <hip/hip_runtime.h>
#include <math.h>

#define N_NODES 16000
#define NGRAPH  16
#define NPG     1000      // nodes per graph
#define H       64
#define KNN     20
#define DIN     8
#define HID     32
#define NLAYERS 4
#define CD      8
#define EPS_BN  1e-5f
#define TI      8         // i-nodes per kNN block (2 per wave)
#define IBLK    125       // 1000/8 exactly — no i-boundary handling needed
#define INFF    __builtin_inff()

// ---------------------------------------------------------------------------
// lc_encode: x[16000,8] -> Linear(8,32)+ELU -> Linear(32,64)+ELU -> h ; also sq
__global__ __launch_bounds__(256) void k_lc_encode(
    const float* __restrict__ x, const float* __restrict__ W1, const float* __restrict__ b1,
    const float* __restrict__ W2, const float* __restrict__ b2,
    float* __restrict__ h, float* __restrict__ sq)
{
    __shared__ float sW1[DIN * HID];
    __shared__ float sb1[HID];
    __shared__ float sW2[HID * H];
    __shared__ float sb2[H];
    __shared__ float sx[4][DIN];
    __shared__ float sa1[4][HID];

    int t = threadIdx.x;
    for (int ix = t; ix < DIN * HID; ix += 256) sW1[ix] = W1[ix];
    for (int ix = t; ix < HID * H;  ix += 256) sW2[ix] = W2[ix];
    if (t < HID) sb1[t] = b1[t];
    if (t < H)   sb2[t] = b2[t];

    int w = t >> 6, lane = t & 63;
    int i = blockIdx.x * 4 + w;
    if (lane < DIN) sx[w][lane] = x[i * DIN + lane];
    __syncthreads();

    int c = lane & 31;
    float a1 = sb1[c];
#pragma unroll
    for (int k = 0; k < DIN; k++) a1 += sx[w][k] * sW1[k * HID + c];
    a1 = a1 > 0.f ? a1 : expm1f(a1);
    if (lane < HID) sa1[w][lane] = a1;
    __syncthreads();

    float acc = sb2[lane];
#pragma unroll
    for (int k = 0; k < HID; k++) acc += sa1[w][k] * sW2[k * H + lane];
    acc = acc > 0.f ? acc : expm1f(acc);
    h[i * H + lane] = acc;

    float s = acc * acc;
#pragma unroll
    for (int off = 32; off > 0; off >>= 1) s += __shfl_xor(s, off);
    if (lane == 0) sq[i] = s;
}

// ---------------------------------------------------------------------------
// kNN history: R1 (launch_bounds 256,4) spilled d2 (10 GB scratch traffic).
// R2/R3/R4/R5 kept 64 floats of d2 state per thread; despite constant-index
// rewrites, VGPR_Count stayed pinned at 128 and 3 GB scratch traffic remained
// -> backend caps this kernel at 128 VGPRs and spills the 64-reg d2 live
// range across the compute->selection boundary. Fix: LOWER THE STATE. 2 i per
// wave => d2 state is 16 named float2 (32 VGPRs), total live ~95 regs.
// No register-array anywhere; LDS arrays may be dynamically indexed.
template<int RG>
__device__ __forceinline__ void knn_group(
    const float* hg, const float* sqg,
    float (&shj)[4][64 * 64], float (&ssqj)[4][64], const float* shi,
    float2 sqiv, float2& ea, float2& eb, float2& ec, float2& ed,
    int t, int w, int lane)
{
    __syncthreads();                      // previous group's readers done
#pragma unroll 4
    for (int p = 0; p < 16; p++) {        // LDS staging (dynamic LDS idx is fine)
        int f = t + 256 * p;              // 0..4095
        int tile = f >> 10;
        int fi = f & 1023;
        int row = fi >> 4, c4 = fi & 15;
        int jl = RG * 256 + tile * 64 + row;
        float4 v = make_float4(0.f, 0.f, 0.f, 0.f);
        if (jl < NPG) v = *(const float4*)(hg + jl * H + c4 * 4);
        *(float4*)(&shj[tile][(row * 16 + (c4 ^ (row & 15))) * 4]) = v;
    }
    {
        int jl = RG * 256 + t;
        ssqj[t >> 6][t & 63] = (jl < NPG) ? sqg[jl] : 0.f;
    }
    __syncthreads();

    // named scalar accumulators aPI: tile P (0..3), i-node I (0..1)
    float a00 = 0.f, a01 = 0.f;
    float a10 = 0.f, a11 = 0.f;
    float a20 = 0.f, a21 = 0.f;
    float a30 = 0.f, a31 = 0.f;

#pragma unroll
    for (int kc = 0; kc < 16; kc++) {
        int bo = (lane * 16 + (kc ^ (lane & 15))) * 4;
        float4 b0 = *(const float4*)(&shj[0][bo]);
        float4 b1 = *(const float4*)(&shj[1][bo]);
        float4 b2 = *(const float4*)(&shj[2][bo]);
        float4 b3 = *(const float4*)(&shj[3][bo]);
        float4 r0 = *(const float4*)(shi + (w * 2 + 0) * H + kc * 4);
        float4 r1 = *(const float4*)(shi + (w * 2 + 1) * H + kc * 4);
        a00 += r0.x*b0.x + r0.y*b0.y + r0.z*b0.z + r0.w*b0.w;
        a01 += r1.x*b0.x + r1.y*b0.y + r1.z*b0.z + r1.w*b0.w;
        a10 += r0.x*b1.x + r0.y*b1.y + r0.z*b1.z + r0.w*b1.w;
        a11 += r1.x*b1.x + r1.y*b1.y + r1.z*b1.z + r1.w*b1.w;
        a20 += r0.x*b2.x + r0.y*b2.y + r0.z*b2.z + r0.w*b2.w;
        a21 += r1.x*b2.x + r1.y*b2.y + r1.z*b2.z + r1.w*b2.w;
        a30 += r0.x*b3.x + r0.y*b3.y + r0.z*b3.z + r0.w*b3.w;
        a31 += r1.x*b3.x + r1.y*b3.y + r1.z*b3.z + r1.w*b3.w;
    }

    // epilogue: all writes to named float2 components (no arrays)
    {
        bool ok = ((RG * 4 + 0) * 64 + lane) < NPG;  float sj = ssqj[0][lane];
        ea.x = ok ? (sqiv.x + sj - 2.f * a00) : INFF;
        ea.y = ok ? (sqiv.y + sj - 2.f * a01) : INFF;
    }
    {
        bool ok = ((RG * 4 + 1) * 64 + lane) < NPG;  float sj = ssqj[1][lane];
        eb.x = ok ? (sqiv.x + sj - 2.f * a10) : INFF;
        eb.y = ok ? (sqiv.y + sj - 2.f * a11) : INFF;
    }
    {
        bool ok = ((RG * 4 + 2) * 64 + lane) < NPG;  float sj = ssqj[2][lane];
        ec.x = ok ? (sqiv.x + sj - 2.f * a20) : INFF;
        ec.y = ok ? (sqiv.y + sj - 2.f * a21) : INFF;
    }
    {
        bool ok = ((RG * 4 + 3) * 64 + lane) < NPG;  float sj = ssqj[3][lane];
        ed.x = ok ? (sqiv.x + sj - 2.f * a30) : INFF;
        ed.y = ok ? (sqiv.y + sj - 2.f * a31) : INFF;
    }
}

// macro-expanded scans/invalidates over the 16 named float2s; C is the
// component token (x or y), i.e. which of the wave's 2 i-nodes.
#define KS(R, C) { float vv = e##R.C; if (vv < bv) { bv = vv; br = R; } }
#define KSCAN15(C) KS(1,C) KS(2,C) KS(3,C) KS(4,C) KS(5,C) KS(6,C) KS(7,C) \
                   KS(8,C) KS(9,C) KS(10,C) KS(11,C) KS(12,C) KS(13,C) KS(14,C) KS(15,C)
#define KI(R, C) e##R.C = (wr == R) ? INFF : e##R.C;
#define KINV16(C) KI(0,C) KI(1,C) KI(2,C) KI(3,C) KI(4,C) KI(5,C) KI(6,C) KI(7,C) \
                  KI(8,C) KI(9,C) KI(10,C) KI(11,C) KI(12,C) KI(13,C) KI(14,C) KI(15,C)

// top-KNN selection for i = i0 + w*2 + II; j = r*64 + lane. 20 rounds of
// wave butterfly argmin, lower-index tiebreak (matches lax.top_k order).
#define SEL_ONE(C, II) { \
    int i_loc = i0 + w * 2 + II; \
    float bv = e0.C; int br = 0; \
    KSCAN15(C) \
    int bj = br * 64 + lane; \
    int myj = 0; \
    _Pragma("unroll 1") \
    for (int round = 0; round < KNN; round++) { \
        float v = bv; int jj = bj; \
        _Pragma("unroll") \
        for (int off = 1; off < 64; off <<= 1) { \
            float ov = __shfl_xor(v, off); \
            int   oj = __shfl_xor(jj, off); \
            if (ov < v || (ov == v && oj < jj)) { v = ov; jj = oj; } \
        } \
        if (lane == round) myj = jj; \
        if ((jj & 63) == lane) { \
            int wr = jj >> 6; \
            KINV16(C) \
            bv = e0.C; br = 0; \
            KSCAN15(C) \
            bj = br * 64 + lane; \
        } \
    } \
    if (lane < KNN) \
        knn[(size_t)(g * NPG + i_loc) * KNN + lane] = g * NPG + myj; \
}

// ---------------------------------------------------------------------------
// Fused kNN. Per block: 8 i-nodes of one graph; wave owns 2 i's; lane owns
// j = lane + 64*r (r=0..15) with d2 in 16 named float2s (32 VGPRs).
__global__ __launch_bounds__(256, 2) void k_knn(
    const float* __restrict__ h, const float* __restrict__ sq, int* __restrict__ knn)
{
    __shared__ float shi[TI * H];        // 8 rows x 64 (broadcast reads -> no pad)
    __shared__ float ssqi[TI];
    __shared__ float shj[4][64 * 64];    // 4 tiles x 64 rows x 16 float4, xor-swizzled
    __shared__ float ssqj[4][64];

    int g  = blockIdx.x / IBLK;
    int ib = blockIdx.x % IBLK;
    int i0 = ib * TI;                    // graph-local, always +TI <= NPG
    int t = threadIdx.x, w = t >> 6, lane = t & 63;
    const float* hg  = h  + (size_t)g * NPG * H;
    const float* sqg = sq + (size_t)g * NPG;

    if (t < TI * 16) {                   // 8 rows x 16 float4
        int row = t >> 4, c4 = t & 15;
        *(float4*)(shi + row * H + c4 * 4) = *(const float4*)(hg + (i0 + row) * H + c4 * 4);
    }
    if (t < TI) ssqi[t] = sqg[i0 + t];
    __syncthreads();

    float2 sqiv = make_float2(ssqi[w * 2 + 0], ssqi[w * 2 + 1]);

    float2 e0, e1, e2, e3, e4, e5, e6, e7, e8, e9, e10, e11, e12, e13, e14, e15;

    knn_group<0>(hg, sqg, shj, ssqj, shi, sqiv, e0,  e1,  e2,  e3,  t, w, lane);
    knn_group<1>(hg, sqg, shj, ssqj, shi, sqiv, e4,  e5,  e6,  e7,  t, w, lane);
    knn_group<2>(hg, sqg, shj, ssqj, shi, sqiv, e8,  e9,  e10, e11, t, w, lane);
    knn_group<3>(hg, sqg, shj, ssqj, shi, sqiv, e12, e13, e14, e15, t, w, lane);

    SEL_ONE(x, 0)
    SEL_ONE(y, 1)
}

// ---------------------------------------------------------------------------
// T = h @ (W1 - W2) + b ; U = h @ W2.   W: [128][64] (rows 0..63 = x_i part).
__global__ __launch_bounds__(256) void k_tu(
    const float* __restrict__ h, const float* __restrict__ W, const float* __restrict__ b,
    float* __restrict__ T, float* __restrict__ U)
{
    __shared__ float sWd[H * H];
    __shared__ float sW2[H * H];
    __shared__ float sh[16 * H];
    __shared__ float sb[H];
    int t = threadIdx.x;
    for (int ix = t; ix < H * H; ix += 256) {
        float w1 = W[ix], w2 = W[H * H + ix];
        sWd[ix] = w1 - w2; sW2[ix] = w2;
    }
    if (t < H) sb[t] = b[t];
    int i0 = blockIdx.x * 16;
    {
        int row = t >> 4, c4 = t & 15;
        *(float4*)(sh + row * H + c4 * 4) = *(const float4*)(h + (size_t)(i0 + row) * H + c4 * 4);
    }
    __syncthreads();

    int lane = t & 63, w = t >> 6;
    int nl = lane >> 4, cg = lane & 15;
    int node = w * 4 + nl;
    float4 tT = make_float4(0.f, 0.f, 0.f, 0.f);
    float4 tU = make_float4(0.f, 0.f, 0.f, 0.f);
#pragma unroll
    for (int e = 0; e < H; e++) {
        float hv = sh[node * H + e];
        float4 wd = *(const float4*)(sWd + e * H + cg * 4);
        float4 w2 = *(const float4*)(sW2 + e * H + cg * 4);
        tT.x += hv * wd.x; tT.y += hv * wd.y; tT.z += hv * wd.z; tT.w += hv * wd.w;
        tU.x += hv * w2.x; tU.y += hv * w2.y; tU.z += hv * w2.z; tU.w += hv * w2.w;
    }
    float4 bb = *(const float4*)(sb + cg * 4);
    tT.x += bb.x; tT.y += bb.y; tT.z += bb.z; tT.w += bb.w;
    int i = i0 + node;
    *(float4*)(T + (size_t)i * H + cg * 4) = tT;
    *(float4*)(U + (size_t)i * H + cg * 4) = tU;
}

// ---------------------------------------------------------------------------
// Aggregate: h_new[i][c] = h[i][c] + a*ELU(sel_k (T[i][c]+U[j_k][c])) + (be - a*m)
__global__ __launch_bounds__(256) void k_aggr(
    const float* __restrict__ hsrc, const float* __restrict__ T, const float* __restrict__ U,
    const int* __restrict__ knn,
    const float* __restrict__ bn_g, const float* __restrict__ bn_b,
    const float* __restrict__ bn_m, const float* __restrict__ bn_v,
    float* __restrict__ hdst, float* __restrict__ sqdst)
{
    int t = threadIdx.x, w = t >> 6, lane = t & 63;
    int i = blockIdx.x * 4 + w;
    float a = bn_g[lane] * rsqrtf(bn_v[lane] + EPS_BN);
    float cshift = bn_b[lane] - a * bn_m[lane];
    float tv = T[(size_t)i * H + lane];
    float mx = -INFF, mn = INFF;
#pragma unroll
    for (int k = 0; k < KNN; k++) {
        int idx = knn[(size_t)i * KNN + k];
        float z = tv + U[(size_t)idx * H + lane];
        mx = fmaxf(mx, z); mn = fminf(mn, z);
    }
    float zsel = (a >= 0.f) ? mx : mn;
    float e = zsel > 0.f ? zsel : expm1f(zsel);
    float val = hsrc[(size_t)i * H + lane] + a * e + cshift;
    hdst[(size_t)i * H + lane] = val;
    float s = val * val;
#pragma unroll
    for (int off = 32; off > 0; off >>= 1) s += __shfl_xor(s, off);
    if (lane == 0) sqdst[i] = s;
}

// ---------------------------------------------------------------------------
// Output heads. out layout: [0,128000): out | [128000,144000): sp | rest: batch
__global__ __launch_bounds__(256) void k_heads(
    const float* __restrict__ h,
    const float* __restrict__ oW1, const float* __restrict__ ob1,
    const float* __restrict__ oW2, const float* __restrict__ ob2,
    const float* __restrict__ oW3, const float* __restrict__ ob3,
    const float* __restrict__ pW1, const float* __restrict__ pb1,
    const float* __restrict__ pW2, const float* __restrict__ pb2,
    const float* __restrict__ pW3, const float* __restrict__ pb3,
    float* __restrict__ out)
{
    __shared__ float soW1[H * 64], soW2[64 * 32], soW3[32 * CD];
    __shared__ float spW1s[H * 64], spW2s[64 * 32], spW3s[32];
    __shared__ float sob1[64], sob2[32], sob3[CD], spb1s[64], spb2s[32], spb3s[1];
    __shared__ float sh[4][H];
    __shared__ float sa[4][64], ssp[4][64];
    __shared__ float so2[4][32], ssp2[4][32];

    int t = threadIdx.x, w = t >> 6, lane = t & 63;
    for (int ix = t; ix < H * 64; ix += 256) { soW1[ix] = oW1[ix]; spW1s[ix] = pW1[ix]; }
    for (int ix = t; ix < 64 * 32; ix += 256) { soW2[ix] = oW2[ix]; spW2s[ix] = pW2[ix]; }
    for (int ix = t; ix < 32 * CD; ix += 256) soW3[ix] = oW3[ix];
    if (t < 32) spW3s[t] = pW3[t];
    if (t < 64) { sob1[t] = ob1[t]; spb1s[t] = pb1[t]; }
    if (t < 32) { sob2[t] = ob2[t]; spb2s[t] = pb2[t]; }
    if (t < CD) sob3[t] = ob3[t];
    if (t == 0) spb3s[0] = pb3[0];
    __syncthreads();

    for (int rep = 0; rep < 4; rep++) {
        int i = blockIdx.x * 16 + rep * 4 + w;
        sh[w][lane] = h[(size_t)i * H + lane];
        __syncthreads();
        float a1 = sob1[lane], p1 = spb1s[lane];
#pragma unroll
        for (int k = 0; k < H; k++) {
            float hv = sh[w][k];
            a1 += hv * soW1[k * 64 + lane];
            p1 += hv * spW1s[k * 64 + lane];
        }
        a1 = a1 > 0.f ? a1 : expm1f(a1);
        p1 = p1 > 0.f ? p1 : expm1f(p1);
        sa[w][lane] = a1; ssp[w][lane] = p1;
        __syncthreads();
        if (lane < 32) {
            float o2 = sob2[lane], q2 = spb2s[lane];
#pragma unroll
            for (int k = 0; k < 64; k++) {
                o2 += sa[w][k] * soW2[k * 32 + lane];
                q2 += ssp[w][k] * spW2s[k * 32 + lane];
            }
            o2 = o2 > 0.f ? o2 : expm1f(o2);
            q2 = q2 > 0.f ? q2 : expm1f(q2);
            so2[w][lane] = o2; ssp2[w][lane] = q2;
        }
        __syncthreads();
        if (lane < CD) {
            float o3 = sob3[lane];
#pragma unroll
            for (int k = 0; k < 32; k++) o3 += so2[w][k] * soW3[k * CD + lane];
            out[(size_t)i * CD + lane] = o3;
        }
        if (lane == 32) {
            float s3 = spb3s[0];
#pragma unroll
            for (int k = 0; k < 32; k++) s3 += ssp2[w][k] * spW3s[k];
            out[(size_t)N_NODES * CD + i] = s3;
        }
        if (lane == 33) out[(size_t)N_NODES * CD + N_NODES + i] = (float)(i / NPG);
        __syncthreads();
    }
}

// ---------------------------------------------------------------------------
extern "C" void kernel_launch(void* const* d_in, const int* in_sizes, int n_in,
                              void* d_out, int out_size, void* d_ws, size_t ws_size,
                              hipStream_t stream)
{
    const float* x     = (const float*)d_in[0];
    const float* lcW1  = (const float*)d_in[2];  const float* lcb1 = (const float*)d_in[3];
    const float* lcW2  = (const float*)d_in[4];  const float* lcb2 = (const float*)d_in[5];
    const float* convW = (const float*)d_in[6];  const float* convb = (const float*)d_in[7];
    const float* bn_g  = (const float*)d_in[8];  const float* bn_b = (const float*)d_in[9];
    const float* bn_m  = (const float*)d_in[10]; const float* bn_v = (const float*)d_in[11];
    const float* outW1 = (const float*)d_in[12]; const float* outb1 = (const float*)d_in[13];
    const float* outW2 = (const float*)d_in[14]; const float* outb2 = (const float*)d_in[15];
    const float* outW3 = (const float*)d_in[16]; const float* outb3 = (const float*)d_in[17];
    const float* spW1  = (const float*)d_in[18]; const float* spb1 = (const float*)d_in[19];
    const float* spW2  = (const float*)d_in[20]; const float* spb2 = (const float*)d_in[21];
    const float* spW3  = (const float*)d_in[22]; const float* spb3 = (const float*)d_in[23];

    float* ws  = (float*)d_ws;
    float* hA  = ws;
    float* hB  = hA + (size_t)N_NODES * H;
    float* sqA = hB + (size_t)N_NODES * H;
    float* sqB = sqA + N_NODES;
    float* T   = sqB + N_NODES;
    float* U   = T + (size_t)N_NODES * H;
    int*   knn = (int*)(U + (size_t)N_NODES * H);

    k_lc_encode<<<N_NODES / 4, 256, 0, stream>>>(x, lcW1, lcb1, lcW2, lcb2, hA, sqA);

    float* src = hA; float* ssq = sqA; float* dst = hB; float* dsq = sqB;
    for (int l = 0; l < NLAYERS; l++) {
        k_knn<<<NGRAPH * IBLK, 256, 0, stream>>>(src, ssq, knn);
        k_tu<<<N_NODES / 16, 256, 0, stream>>>(src, convW + (size_t)l * 2 * H * H,
                                               convb + (size_t)l * H, T, U);
        k_aggr<<<N_NODES / 4, 256, 0, stream>>>(src, T, U, knn,
                                                bn_g + (size_t)l * H, bn_b + (size_t)l * H,
                                                bn_m + (size_t)l * H, bn_v + (size_t)l * H,
                                                dst, dsq);
        float* tmp = src; src = dst; dst = tmp;
        tmp = ssq; ssq = dsq; dsq = tmp;
    }

    k_heads<<<N_NODES / 16, 256, 0, stream>>>(src,
        outW1, outb1, outW2, outb2, outW3, outb3,
        spW1, spb1, spW2, spb2, spW3, spb3, (float*)d_out);
}

// Round 7
// 1172.137 us; speedup vs baseline: 7.8766x; 7.8766x over previous
//
#include <hip/hip_runtime.h>
#include <math.h>

#define N_NODES 16000
#define NGRAPH  16
#define NPG     1000      // nodes per graph
#define H       64
#define KNN     20
#define DIN     8
#define HID     32
#define NLAYERS 4
#define CD      8
#define EPS_BN  1e-5f
#define TI      8         // i-nodes per kNN block (2 per wave)
#define IBLK    125       // 1000/8 exactly
#define INFF    __builtin_inff()

// ---------------------------------------------------------------------------
// lc_encode: x[16000,8] -> Linear(8,32)+ELU -> Linear(32,64)+ELU -> h ; also sq
__global__ __launch_bounds__(256) void k_lc_encode(
    const float* __restrict__ x, const float* __restrict__ W1, const float* __restrict__ b1,
    const float* __restrict__ W2, const float* __restrict__ b2,
    float* __restrict__ h, float* __restrict__ sq)
{
    __shared__ float sW1[DIN * HID];
    __shared__ float sb1[HID];
    __shared__ float sW2[HID * H];
    __shared__ float sb2[H];
    __shared__ float sx[4][DIN];
    __shared__ float sa1[4][HID];

    int t = threadIdx.x;
    for (int ix = t; ix < DIN * HID; ix += 256) sW1[ix] = W1[ix];
    for (int ix = t; ix < HID * H;  ix += 256) sW2[ix] = W2[ix];
    if (t < HID) sb1[t] = b1[t];
    if (t < H)   sb2[t] = b2[t];

    int w = t >> 6, lane = t & 63;
    int i = blockIdx.x * 4 + w;
    if (lane < DIN) sx[w][lane] = x[i * DIN + lane];
    __syncthreads();

    int c = lane & 31;
    float a1 = sb1[c];
#pragma unroll
    for (int k = 0; k < DIN; k++) a1 += sx[w][k] * sW1[k * HID + c];
    a1 = a1 > 0.f ? a1 : expm1f(a1);
    if (lane < HID) sa1[w][lane] = a1;
    __syncthreads();

    float acc = sb2[lane];
#pragma unroll
    for (int k = 0; k < HID; k++) acc += sa1[w][k] * sW2[k * H + lane];
    acc = acc > 0.f ? acc : expm1f(acc);
    h[i * H + lane] = acc;

    float s = acc * acc;
#pragma unroll
    for (int off = 32; off > 0; off >>= 1) s += __shfl_xor(s, off);
    if (lane == 0) sq[i] = s;
}

// ---------------------------------------------------------------------------
// Fused kNN, round 7 design: the d2 working set lives in LDS, not registers.
// History: R1-R6 all tried to keep 1000 d2 values per wave in VGPRs; every
// formulation (launch-bounds caps, constant-index templates, named scalars)
// left VGPR_Count pinned at 128 with 3-4.5 GB/dispatch of scratch RMW traffic
// (WRITE_SIZE vs 1.4 MB legit) and VALUBusy ~5%. The backend spills the
// compute->selection live range no matter how the source is shaped. LDS makes
// that impossible: dynamic indexing is native, no alloca, no regalloc stake.
//
// Block: 8 i-nodes of one graph; wave owns i = i0+w*2+{0,1}; lane owns
// j = r*64+lane (r=0..15, 1024 padded slots, j>=1000 = +inf).
// sd2 rows are written lane-consecutive (conflict-free) and re-scanned from
// LDS during selection. Only scalars live across barriers.
__global__ __launch_bounds__(256, 2) void k_knn(
    const float* __restrict__ h, const float* __restrict__ sq, int* __restrict__ knn)
{
    __shared__ float shi[TI * H];        // 8 i-rows x 64 (wave-uniform broadcast reads)
    __shared__ float ssqi[TI];
    __shared__ float shj[2][64 * 64];    // 2 j-tiles x 64 rows x 16 float4, xor-swizzled
    __shared__ float ssqj[2][64];
    __shared__ float sd2[TI][1024];      // the d2 working set  (32 KB)

    int g  = blockIdx.x / IBLK;
    int ib = blockIdx.x % IBLK;
    int i0 = ib * TI;                    // graph-local; i0+TI <= NPG always
    int t = threadIdx.x, w = t >> 6, lane = t & 63;
    const float* hg  = h  + (size_t)g * NPG * H;
    const float* sqg = sq + (size_t)g * NPG;

    if (t < TI * 16) {                   // 8 rows x 16 float4
        int row = t >> 4, c4 = t & 15;
        *(float4*)(shi + row * H + c4 * 4) = *(const float4*)(hg + (i0 + row) * H + c4 * 4);
    }
    if (t < TI) ssqi[t] = sqg[i0 + t];
    __syncthreads();

    float sqi0 = ssqi[w * 2 + 0];
    float sqi1 = ssqi[w * 2 + 1];

    // ---- compute phase: 8 groups x 2 j-tiles of 64 ----
    for (int rg = 0; rg < 8; rg++) {
        if (rg) __syncthreads();
        // stage 2 tiles (128 j-rows x 64 floats) = 2048 float4, 8 per thread
#pragma unroll 4
        for (int p = 0; p < 8; p++) {
            int f = t + 256 * p;         // 0..2047
            int tile = f >> 10;
            int fi = f & 1023;
            int row = fi >> 4, c4 = fi & 15;
            int jl = rg * 128 + tile * 64 + row;
            float4 v = make_float4(0.f, 0.f, 0.f, 0.f);
            if (jl < NPG) v = *(const float4*)(hg + jl * H + c4 * 4);
            *(float4*)(&shj[tile][(row * 16 + (c4 ^ (row & 15))) * 4]) = v;
        }
        if (t < 128) {
            int jl = rg * 128 + t;
            ssqj[t >> 6][t & 63] = (jl < NPG) ? sqg[jl] : 0.f;
        }
        __syncthreads();

        float a00 = 0.f, a01 = 0.f, a10 = 0.f, a11 = 0.f;  // aTI: tile T, i-node I
#pragma unroll
        for (int kc = 0; kc < 16; kc++) {
            int bo = (lane * 16 + (kc ^ (lane & 15))) * 4;
            float4 b0 = *(const float4*)(&shj[0][bo]);
            float4 b1 = *(const float4*)(&shj[1][bo]);
            float4 r0 = *(const float4*)(shi + (w * 2 + 0) * H + kc * 4);
            float4 r1 = *(const float4*)(shi + (w * 2 + 1) * H + kc * 4);
            a00 += r0.x*b0.x + r0.y*b0.y + r0.z*b0.z + r0.w*b0.w;
            a01 += r1.x*b0.x + r1.y*b0.y + r1.z*b0.z + r1.w*b0.w;
            a10 += r0.x*b1.x + r0.y*b1.y + r0.z*b1.z + r0.w*b1.w;
            a11 += r1.x*b1.x + r1.y*b1.y + r1.z*b1.z + r1.w*b1.w;
        }
        int j0 = rg * 128 + lane;
        int j1 = j0 + 64;
        float sj0 = ssqj[0][lane];
        float sj1 = ssqj[1][lane];
        sd2[w * 2 + 0][rg * 128 + lane]      = (j0 < NPG) ? (sqi0 + sj0 - 2.f * a00) : INFF;
        sd2[w * 2 + 1][rg * 128 + lane]      = (j0 < NPG) ? (sqi1 + sj0 - 2.f * a01) : INFF;
        sd2[w * 2 + 0][rg * 128 + 64 + lane] = (j1 < NPG) ? (sqi0 + sj1 - 2.f * a10) : INFF;
        sd2[w * 2 + 1][rg * 128 + 64 + lane] = (j1 < NPG) ? (sqi1 + sj1 - 2.f * a11) : INFF;
    }
    __syncthreads();

    // ---- selection phase: 20 rounds of wave butterfly argmin per i ----
    // (lower-index tiebreak == lax.top_k stable order; verified R1-R6)
    for (int II = 0; II < 2; II++) {
        float* row = &sd2[w * 2 + II][0];
        float bv = INFF; int br = 0;
#pragma unroll
        for (int r = 0; r < 16; r++) {
            float v = row[r * 64 + lane];
            if (v < bv) { bv = v; br = r; }
        }
        int bj = br * 64 + lane;
        int myj = 0;
#pragma unroll 1
        for (int round = 0; round < KNN; round++) {
            float v = bv; int jj = bj;
#pragma unroll
            for (int off = 1; off < 64; off <<= 1) {
                float ov = __shfl_xor(v, off);
                int   oj = __shfl_xor(jj, off);
                if (ov < v || (ov == v && oj < jj)) { v = ov; jj = oj; }
            }
            if (lane == round) myj = jj;     // lanes 0..19 collect winners in order
            if ((jj & 63) == lane) {         // owner invalidates + rescans its 16 slots
                row[jj] = INFF;
                bv = INFF; br = 0;
#pragma unroll
                for (int r = 0; r < 16; r++) {
                    float vv = row[r * 64 + lane];
                    if (vv < bv) { bv = vv; br = r; }
                }
                bj = br * 64 + lane;
            }
        }
        if (lane < KNN)
            knn[(size_t)(g * NPG + i0 + w * 2 + II) * KNN + lane] = g * NPG + myj;
    }
}

// ---------------------------------------------------------------------------
// T = h @ (W1 - W2) + b ; U = h @ W2.   W: [128][64] (rows 0..63 = x_i part).
__global__ __launch_bounds__(256) void k_tu(
    const float* __restrict__ h, const float* __restrict__ W, const float* __restrict__ b,
    float* __restrict__ T, float* __restrict__ U)
{
    __shared__ float sWd[H * H];
    __shared__ float sW2[H * H];
    __shared__ float sh[16 * H];
    __shared__ float sb[H];
    int t = threadIdx.x;
    for (int ix = t; ix < H * H; ix += 256) {
        float w1 = W[ix], w2 = W[H * H + ix];
        sWd[ix] = w1 - w2; sW2[ix] = w2;
    }
    if (t < H) sb[t] = b[t];
    int i0 = blockIdx.x * 16;
    {
        int row = t >> 4, c4 = t & 15;
        *(float4*)(sh + row * H + c4 * 4) = *(const float4*)(h + (size_t)(i0 + row) * H + c4 * 4);
    }
    __syncthreads();

    int lane = t & 63, w = t >> 6;
    int nl = lane >> 4, cg = lane & 15;
    int node = w * 4 + nl;
    float4 tT = make_float4(0.f, 0.f, 0.f, 0.f);
    float4 tU = make_float4(0.f, 0.f, 0.f, 0.f);
#pragma unroll
    for (int e = 0; e < H; e++) {
        float hv = sh[node * H + e];
        float4 wd = *(const float4*)(sWd + e * H + cg * 4);
        float4 w2 = *(const float4*)(sW2 + e * H + cg * 4);
        tT.x += hv * wd.x; tT.y += hv * wd.y; tT.z += hv * wd.z; tT.w += hv * wd.w;
        tU.x += hv * w2.x; tU.y += hv * w2.y; tU.z += hv * w2.z; tU.w += hv * w2.w;
    }
    float4 bb = *(const float4*)(sb + cg * 4);
    tT.x += bb.x; tT.y += bb.y; tT.z += bb.z; tT.w += bb.w;
    int i = i0 + node;
    *(float4*)(T + (size_t)i * H + cg * 4) = tT;
    *(float4*)(U + (size_t)i * H + cg * 4) = tU;
}

// ---------------------------------------------------------------------------
// Aggregate: h_new[i][c] = h[i][c] + a*ELU(sel_k (T[i][c]+U[j_k][c])) + (be - a*m)
__global__ __launch_bounds__(256) void k_aggr(
    const float* __restrict__ hsrc, const float* __restrict__ T, const float* __restrict__ U,
    const int* __restrict__ knn,
    const float* __restrict__ bn_g, const float* __restrict__ bn_b,
    const float* __restrict__ bn_m, const float* __restrict__ bn_v,
    float* __restrict__ hdst, float* __restrict__ sqdst)
{
    int t = threadIdx.x, w = t >> 6, lane = t & 63;
    int i = blockIdx.x * 4 + w;
    float a = bn_g[lane] * rsqrtf(bn_v[lane] + EPS_BN);
    float cshift = bn_b[lane] - a * bn_m[lane];
    float tv = T[(size_t)i * H + lane];
    float mx = -INFF, mn = INFF;
#pragma unroll
    for (int k = 0; k < KNN; k++) {
        int idx = knn[(size_t)i * KNN + k];
        float z = tv + U[(size_t)idx * H + lane];
        mx = fmaxf(mx, z); mn = fminf(mn, z);
    }
    float zsel = (a >= 0.f) ? mx : mn;
    float e = zsel > 0.f ? zsel : expm1f(zsel);
    float val = hsrc[(size_t)i * H + lane] + a * e + cshift;
    hdst[(size_t)i * H + lane] = val;
    float s = val * val;
#pragma unroll
    for (int off = 32; off > 0; off >>= 1) s += __shfl_xor(s, off);
    if (lane == 0) sqdst[i] = s;
}

// ---------------------------------------------------------------------------
// Output heads. out layout: [0,128000): out | [128000,144000): sp | rest: batch
__global__ __launch_bounds__(256) void k_heads(
    const float* __restrict__ h,
    const float* __restrict__ oW1, const float* __restrict__ ob1,
    const float* __restrict__ oW2, const float* __restrict__ ob2,
    const float* __restrict__ oW3, const float* __restrict__ ob3,
    const float* __restrict__ pW1, const float* __restrict__ pb1,
    const float* __restrict__ pW2, const float* __restrict__ pb2,
    const float* __restrict__ pW3, const float* __restrict__ pb3,
    float* __restrict__ out)
{
    __shared__ float soW1[H * 64], soW2[64 * 32], soW3[32 * CD];
    __shared__ float spW1s[H * 64], spW2s[64 * 32], spW3s[32];
    __shared__ float sob1[64], sob2[32], sob3[CD], spb1s[64], spb2s[32], spb3s[1];
    __shared__ float sh[4][H];
    __shared__ float sa[4][64], ssp[4][64];
    __shared__ float so2[4][32], ssp2[4][32];

    int t = threadIdx.x, w = t >> 6, lane = t & 63;
    for (int ix = t; ix < H * 64; ix += 256) { soW1[ix] = oW1[ix]; spW1s[ix] = pW1[ix]; }
    for (int ix = t; ix < 64 * 32; ix += 256) { soW2[ix] = oW2[ix]; spW2s[ix] = pW2[ix]; }
    for (int ix = t; ix < 32 * CD; ix += 256) soW3[ix] = oW3[ix];
    if (t < 32) spW3s[t] = pW3[t];
    if (t < 64) { sob1[t] = ob1[t]; spb1s[t] = pb1[t]; }
    if (t < 32) { sob2[t] = ob2[t]; spb2s[t] = pb2[t]; }
    if (t < CD) sob3[t] = ob3[t];
    if (t == 0) spb3s[0] = pb3[0];
    __syncthreads();

    for (int rep = 0; rep < 4; rep++) {
        int i = blockIdx.x * 16 + rep * 4 + w;
        sh[w][lane] = h[(size_t)i * H + lane];
        __syncthreads();
        float a1 = sob1[lane], p1 = spb1s[lane];
#pragma unroll
        for (int k = 0; k < H; k++) {
            float hv = sh[w][k];
            a1 += hv * soW1[k * 64 + lane];
            p1 += hv * spW1s[k * 64 + lane];
        }
        a1 = a1 > 0.f ? a1 : expm1f(a1);
        p1 = p1 > 0.f ? p1 : expm1f(p1);
        sa[w][lane] = a1; ssp[w][lane] = p1;
        __syncthreads();
        if (lane < 32) {
            float o2 = sob2[lane], q2 = spb2s[lane];
#pragma unroll
            for (int k = 0; k < 64; k++) {
                o2 += sa[w][k] * soW2[k * 32 + lane];
                q2 += ssp[w][k] * spW2s[k * 32 + lane];
            }
            o2 = o2 > 0.f ? o2 : expm1f(o2);
            q2 = q2 > 0.f ? q2 : expm1f(q2);
            so2[w][lane] = o2; ssp2[w][lane] = q2;
        }
        __syncthreads();
        if (lane < CD) {
            float o3 = sob3[lane];
#pragma unroll
            for (int k = 0; k < 32; k++) o3 += so2[w][k] * soW3[k * CD + lane];
            out[(size_t)i * CD + lane] = o3;
        }
        if (lane == 32) {
            float s3 = spb3s[0];
#pragma unroll
            for (int k = 0; k < 32; k++) s3 += ssp2[w][k] * spW3s[k];
            out[(size_t)N_NODES * CD + i] = s3;
        }
        if (lane == 33) out[(size_t)N_NODES * CD + N_NODES + i] = (float)(i / NPG);
        __syncthreads();
    }
}

// ---------------------------------------------------------------------------
extern "C" void kernel_launch(void* const* d_in, const int* in_sizes, int n_in,
                              void* d_out, int out_size, void* d_ws, size_t ws_size,
                              hipStream_t stream)
{
    const float* x     = (const float*)d_in[0];
    const float* lcW1  = (const float*)d_in[2];  const float* lcb1 = (const float*)d_in[3];
    const float* lcW2  = (const float*)d_in[4];  const float* lcb2 = (const float*)d_in[5];
    const float* convW = (const float*)d_in[6];  const float* convb = (const float*)d_in[7];
    const float* bn_g  = (const float*)d_in[8];  const float* bn_b = (const float*)d_in[9];
    const float* bn_m  = (const float*)d_in[10]; const float* bn_v = (const float*)d_in[11];
    const float* outW1 = (const float*)d_in[12]; const float* outb1 = (const float*)d_in[13];
    const float* outW2 = (const float*)d_in[14]; const float* outb2 = (const float*)d_in[15];
    const float* outW3 = (const float*)d_in[16]; const float* outb3 = (const float*)d_in[17];
    const float* spW1  = (const float*)d_in[18]; const float* spb1 = (const float*)d_in[19];
    const float* spW2  = (const float*)d_in[20]; const float* spb2 = (const float*)d_in[21];
    const float* spW3  = (const float*)d_in[22]; const float* spb3 = (const float*)d_in[23];

    float* ws  = (float*)d_ws;
    float* hA  = ws;
    float* hB  = hA + (size_t)N_NODES * H;
    float* sqA = hB + (size_t)N_NODES * H;
    float* sqB = sqA + N_NODES;
    float* T   = sqB + N_NODES;
    float* U   = T + (size_t)N_NODES * H;
    int*   knn = (int*)(U + (size_t)N_NODES * H);

    k_lc_encode<<<N_NODES / 4, 256, 0, stream>>>(x, lcW1, lcb1, lcW2, lcb2, hA, sqA);

    float* src = hA; float* ssq = sqA; float* dst = hB; float* dsq = sqB;
    for (int l = 0; l < NLAYERS; l++) {
        k_knn<<<NGRAPH * IBLK, 256, 0, stream>>>(src, ssq, knn);
        k_tu<<<N_NODES / 16, 256, 0, stream>>>(src, convW + (size_t)l * 2 * H * H,
                                               convb + (size_t)l * H, T, U);
        k_aggr<<<N_NODES / 4, 256, 0, stream>>>(src, T, U, knn,
                                                bn_g + (size_t)l * H, bn_b + (size_t)l * H,
                                                bn_m + (size_t)l * H, bn_v + (size_t)l * H,
                                                dst, dsq);
        float* tmp = src; src = dst; dst = tmp;
        tmp = ssq; ssq = dsq; dsq = tmp;
    }

    k_heads<<<N_NODES / 16, 256, 0, stream>>>(src,
        outW1, outb1, outW2, outb2, outW3, outb3,
        spW1, spb1, spW2, spb2, spW3, spb3, (float*)d_out);
}